// Round 1
// baseline (111.240 us; speedup 1.0000x reference)
//
#include <hip/hip_runtime.h>
#include <math.h>

#define NH 256
#define NW 256
#define NP (NH*NW)
#define NF 640

__device__ __constant__ float kFOCAL = 3.7320508075688776f; // 1/tan(15 deg)
#define EYE_Z 2.732f
#define BIGF 1.0e10f
#define EPSF 1.0e-8f

// ws layout: [0, 30720)         faceData: NF * 3 * float4
//            [32768, 32768+655360) texPad: NF * 64 * float4 (tanh'd, ch padded to 4)

__global__ void prep_kernel(const float* __restrict__ vertices,
                            const int* __restrict__ faces,
                            const float* __restrict__ textures,
                            const float* __restrict__ angle,
                            float4* __restrict__ faceData,
                            float4* __restrict__ texPad,
                            float* __restrict__ out)
{
    int b = blockIdx.x;
    int tid = threadIdx.x;
    if (b < 480) {
        // tanh + pad: 480*256 == 122880 == NF*4*4*4*3
        int e = b * 256 + tid;
        float v = tanhf(textures[e]);
        int fidx = e / 192;
        int r = e - fidx * 192;
        int t = r / 3;
        int ch = r - t * 3;
        ((float*)&texPad[fidx * 64 + t])[ch] = v;
    } else if (b < 483) {
        int j = (b - 480) * 256 + tid;
        if (j < NF) {
            float th = angle[0] * 6.283185307179586f;
            float cth = cosf(th), sth = sinf(th);
            float vx[3], vy[3], vd[3];
#pragma unroll
            for (int k = 0; k < 3; k++) {
                int vi = faces[j * 3 + k];
                float x = vertices[vi * 3 + 0];
                float y = vertices[vi * 3 + 1];
                float z = vertices[vi * 3 + 2];
                float xr = cth * x + sth * z;
                float zr = -sth * x + cth * z;
                float depth = EYE_Z - zr;
                vx[k] = kFOCAL * xr / depth;
                vy[k] = kFOCAL * y / depth;
                vd[k] = depth;
            }
            float ax = vx[0], ay = vy[0], bx = vx[1], by = vy[1], cx = vx[2], cy = vy[2];
            float area = (bx - ax) * (cy - ay) - (by - ay) * (cx - ax);
            float4 d0, d1, d2;
            if (fabsf(area) > EPSF) {
                float inv = 1.0f / area;
                // w0 = ((cx-bx)*(py-by) - (cy-by)*(px-bx)) / area  = A0*px + B0*py + C0
                float A0 = -(cy - by) * inv;
                float B0 = (cx - bx) * inv;
                float C0 = (bx * (cy - by) - by * (cx - bx)) * inv;
                // w1 = ((ax-cx)*(py-cy) - (ay-cy)*(px-cx)) / area
                float A1 = -(ay - cy) * inv;
                float B1 = (ax - cx) * inv;
                float C1 = (cx * (ay - cy) - cy * (ax - cx)) * inv;
                // z = w0*fd0 + w1*fd1 + (1-w0-w1)*fd2 = zA*w0 + zB*w1 + zC
                float zA = vd[0] - vd[2];
                float zB = vd[1] - vd[2];
                float zC = vd[2];
                d0 = make_float4(A0, B0, C0, A1);
                d1 = make_float4(B1, C1, zA, zB);
                d2 = make_float4(zC, 0.f, 0.f, 0.f);
            } else {
                // invalid face: force w0 = -1 (never inside), z = 0 (fails z>EPS too)
                d0 = make_float4(0.f, 0.f, -1.f, 0.f);
                d1 = make_float4(0.f, -1.f, 0.f, 0.f);
                d2 = make_float4(0.f, 0.f, 0.f, 0.f);
            }
            faceData[j * 3 + 0] = d0;
            faceData[j * 3 + 1] = d1;
            faceData[j * 3 + 2] = d2;
        }
    } else {
        if (tid == 0) out[0] = 0.0f;
    }
}

__global__ __launch_bounds__(256) void render_kernel(
    const float4* __restrict__ faceData,
    const float4* __restrict__ texPad,
    const float* __restrict__ ref,
    float* __restrict__ out)
{
    __shared__ float4 sf[NF * 3];
    __shared__ float wsum[4];
    int tid = threadIdx.x;
    for (int i = tid; i < NF * 3; i += 256) sf[i] = faceData[i];
    __syncthreads();

    int p = blockIdx.x * 256 + tid;
    int row = p >> 8;
    int colj = p & 255;
    float px = ((float)colj + 0.5f) * (1.0f / 128.0f) - 1.0f;
    float py = 1.0f - ((float)row + 0.5f) * (1.0f / 128.0f);

    float zmin = BIGF;
    int best = 0;
    float bw0 = 0.f, bw1 = 0.f;
#pragma unroll 4
    for (int f = 0; f < NF; ++f) {
        float4 d0 = sf[f * 3 + 0];
        float4 d1 = sf[f * 3 + 1];
        float zC = sf[f * 3 + 2].x;
        float w0 = fmaf(d0.x, px, fmaf(d0.y, py, d0.z));
        float w1 = fmaf(d0.w, px, fmaf(d1.x, py, d1.y));
        float w2 = 1.f - w0 - w1;
        float z = fmaf(d1.z, w0, fmaf(d1.w, w1, zC));
        bool ok = (w0 >= 0.f) && (w1 >= 0.f) && (w2 >= 0.f) && (z > EPSF) && (z < zmin);
        zmin = ok ? z : zmin;
        best = ok ? f : best;
        bw0 = ok ? w0 : bw0;
        bw1 = ok ? w1 : bw1;
    }
    bool hit = zmin < 0.5f * BIGF;

    float pw2 = 1.f - bw0 - bw1;
    float u0 = fminf(fmaxf(bw0, 0.f), 1.f) * 3.f;
    float u1 = fminf(fmaxf(bw1, 0.f), 1.f) * 3.f;
    float u2 = fminf(fmaxf(pw2, 0.f), 1.f) * 3.f;
    int i0 = min(max((int)floorf(u0), 0), 2);
    int i1 = min(max((int)floorf(u1), 0), 2);
    int i2 = min(max((int)floorf(u2), 0), 2);
    float fr0 = u0 - (float)i0;
    float fr1 = u1 - (float)i1;
    float fr2 = u2 - (float)i2;

    const float4* tb = texPad + best * 64;
    float cr = 0.f, cg = 0.f, cb = 0.f;
#pragma unroll
    for (int a = 0; a < 2; a++) {
#pragma unroll
        for (int bb = 0; bb < 2; bb++) {
#pragma unroll
            for (int cc = 0; cc < 2; cc++) {
                int idx = (i0 + a) * 16 + (i1 + bb) * 4 + (i2 + cc);
                float w = (a ? fr0 : 1.f - fr0) * (bb ? fr1 : 1.f - fr1) * (cc ? fr2 : 1.f - fr2);
                float4 t = tb[idx];
                cr = fmaf(w, t.x, cr);
                cg = fmaf(w, t.y, cg);
                cb = fmaf(w, t.z, cb);
            }
        }
    }
    if (!hit) { cr = 0.f; cg = 0.f; cb = 0.f; }

    float e0 = cr - ref[p];
    float e1 = cg - ref[NP + p];
    float e2 = cb - ref[2 * NP + p];
    float e = fmaf(e0, e0, fmaf(e1, e1, e2 * e2));

#pragma unroll
    for (int off = 32; off > 0; off >>= 1) e += __shfl_down(e, off, 64);
    int lane = tid & 63;
    int wid = tid >> 6;
    if (lane == 0) wsum[wid] = e;
    __syncthreads();
    if (tid == 0) {
        float s = wsum[0] + wsum[1] + wsum[2] + wsum[3];
        atomicAdd(out, s);
    }
}

extern "C" void kernel_launch(void* const* d_in, const int* in_sizes, int n_in,
                              void* d_out, int out_size, void* d_ws, size_t ws_size,
                              hipStream_t stream) {
    const float* vertices = (const float*)d_in[0];
    const int* faces = (const int*)d_in[1];
    const float* textures = (const float*)d_in[2];
    const float* image_ref = (const float*)d_in[3];
    const float* angle = (const float*)d_in[4];
    float* out = (float*)d_out;

    float4* faceData = (float4*)d_ws;                          // 30720 B
    float4* texPad = (float4*)((char*)d_ws + 32768);           // 655360 B

    prep_kernel<<<484, 256, 0, stream>>>(vertices, faces, textures, angle,
                                         faceData, texPad, out);
    render_kernel<<<256, 256, 0, stream>>>(faceData, texPad, image_ref, out);
}